// Round 17
// baseline (73.581 us; speedup 1.0000x reference)
//
#include <hip/hip_runtime.h>
#include <math.h>

constexpr int CBS   = 8;
constexpr int CN    = 1024;
constexpr int CFIN  = 256;
constexpr int CNH   = 8;
constexpr int CFOUT = 64;

using f32x4 = __attribute__((ext_vector_type(4))) float;
using s16x8 = __attribute__((ext_vector_type(8))) short;

__device__ __forceinline__ short f2bf(float x) {
  __bf16 b = (__bf16)x;
  return __builtin_bit_cast(short, b);
}
__device__ __forceinline__ float bf2f(short s) {
  __bf16 b = __builtin_bit_cast(__bf16, s);
  return (float)b;
}
__device__ __forceinline__ unsigned int pkhi(float a, float b) {
  return (unsigned int)(unsigned short)f2bf(a) |
         ((unsigned int)(unsigned short)f2bf(b) << 16);
}

// ---------------------------------------------------------------------------
// prep [VERIFIED round-14/16 verbatim]: conv_h -> A-fragment-native hh/hl
// (0..1023), conv_w -> B-fragment-native wh/wl (1024..1031), packT fat-wave
// -> maskT[b][jw32][i] (1032..3079).
// ---------------------------------------------------------------------------
__global__ __launch_bounds__(256) void prep(
    const float* __restrict__ h, const float* __restrict__ w,
    const int* __restrict__ adj,
    unsigned int* __restrict__ hh, unsigned int* __restrict__ hl,
    unsigned int* __restrict__ wh, unsigned int* __restrict__ wl,
    unsigned int* __restrict__ maskT) {
  const int blk = blockIdx.x, t = threadIdx.x;
  if (blk < 1024) {
    size_t i = (size_t)blk * 256 + t;          // uint4 index in [0, 262144)
    const int gi = (int)(i & 31);
    const int n  = (int)((i >> 5) & 1023);
    const int b  = (int)(i >> 15);
    const float4* src = (const float4*)(h + i * 8);
    float4 a = src[0], bb = src[1];
    float v[8] = {a.x, a.y, a.z, a.w, bb.x, bb.y, bb.z, bb.w};
    unsigned int hw[4], lw[4];
    #pragma unroll
    for (int p = 0; p < 4; ++p) {
      float x0 = v[2 * p], x1 = v[2 * p + 1];
      short h0 = f2bf(x0), h1 = f2bf(x1);
      hw[p] = (unsigned int)(unsigned short)h0 | ((unsigned int)(unsigned short)h1 << 16);
      lw[p] = pkhi(x0 - bf2f(h0), x1 - bf2f(h1));
    }
    const int RT = n >> 4, l15v = n & 15, kwI = gi >> 2, g4v = gi & 3;
    size_t dst = (((size_t)b * 64 + RT) * 8 + kwI) * 64 + (g4v * 16 + l15v);
    ((uint4*)hh)[dst] = make_uint4(hw[0], hw[1], hw[2], hw[3]);
    ((uint4*)hl)[dst] = make_uint4(lw[0], lw[1], lw[2], lw[3]);
  } else if (blk < 1032) {
    const int head = blk - 1024;
    const int o = t & 63, kc = (t >> 6) * 64;
    const int g = o >> 4, l15v = o & 15;
    const float* wg = w + (size_t)head * CFIN * CFOUT;
    #pragma unroll
    for (int j = 0; j < 8; ++j) {
      const int gi = (kc >> 3) + j;            // 0..31
      const int kwI = gi >> 2, g4v = gi & 3;
      unsigned int hw[4], lw[4];
      #pragma unroll
      for (int p = 0; p < 4; ++p) {
        int k = gi * 8 + 2 * p;
        float x0 = wg[(size_t)k * 64 + o], x1 = wg[(size_t)(k + 1) * 64 + o];
        short h0 = f2bf(x0), h1 = f2bf(x1);
        hw[p] = (unsigned int)(unsigned short)h0 | ((unsigned int)(unsigned short)h1 << 16);
        lw[p] = pkhi(x0 - bf2f(h0), x1 - bf2f(h1));
      }
      size_t dst = (((size_t)head * 4 + g) * 8 + kwI) * 64 + (g4v * 16 + l15v);
      ((uint4*)wh)[dst] = make_uint4(hw[0], hw[1], hw[2], hw[3]);
      ((uint4*)wl)[dst] = make_uint4(lw[0], lw[1], lw[2], lw[3]);
    }
  } else {
    const int lane = t & 63, wv = t >> 6;
    const long long bi = (long long)(blk - 1032) * 4 + wv;   // b*1024 + i
    const int b = (int)(bi >> 10), i = (int)(bi & 1023);
    const int* ap = adj + bi * 1024 + lane;
    int a[16];
    #pragma unroll
    for (int jw = 0; jw < 16; ++jw) a[jw] = ap[jw * 64];     // 16 loads in flight
    #pragma unroll
    for (int jw = 0; jw < 16; ++jw) {
      unsigned long long m = __ballot(a[jw] > 0);
      if (lane == 0) {
        maskT[((size_t)b * 32 + jw * 2 + 0) * 1024 + i] = (unsigned int)m;
        maskT[((size_t)b * 32 + jw * 2 + 1) * 1024 + i] = (unsigned int)(m >> 32);
      }
    }
  }
}

// ---------------------------------------------------------------------------
// liteF [VERIFIED round-14/16 verbatim]: 512 blocks. hp = h@w via hi/lo
// 3-MFMA split (fragment-native A/B loads); epilogue writes vsrc/vdst
// (×log2e) and fragment-native fB hi/lo.
// ---------------------------------------------------------------------------
__global__ __launch_bounds__(256) void liteF(
    const unsigned int* __restrict__ hh, const unsigned int* __restrict__ hl,
    const unsigned int* __restrict__ wh, const unsigned int* __restrict__ wl,
    const float* __restrict__ a_src, const float* __restrict__ a_dst,
    unsigned int* __restrict__ fBh, unsigned int* __restrict__ fBl,
    float* __restrict__ vsrc, float* __restrict__ vdst) {
  __shared__ float tileT[4][64 * 33];   // per-wave [o][n_local], pad 33
  const int bid = blockIdx.x, t = threadIdx.x;
  const int lane = t & 63, wid = t >> 6;
  const int blk = (bid & 7) * 64 + (bid >> 3);   // XCD swizzle: one b per XCD
  const int bh = blk >> 3, head = bh & 7, b = bh >> 3;
  const int row0 = (blk & 7) * 128 + wid * 32;
  const int l15 = lane & 15, g4 = lane >> 4;
  const float LOG2E = 1.44269504088896340736f;

  const uint4* A0 = (const uint4*)hh + (((size_t)b * 64 + (row0 >> 4)) * 8) * 64 + lane;
  const uint4* A1 = (const uint4*)hl + (((size_t)b * 64 + (row0 >> 4)) * 8) * 64 + lane;
  const uint4* B0 = (const uint4*)wh + ((size_t)head * 4 * 8) * 64 + lane;
  const uint4* B1 = (const uint4*)wl + ((size_t)head * 4 * 8) * 64 + lane;

  f32x4 acc[2][4];
  #pragma unroll
  for (int f = 0; f < 2; ++f)
    #pragma unroll
    for (int g = 0; g < 4; ++g) acc[f][g] = (f32x4){0.f, 0.f, 0.f, 0.f};

  for (int kwI = 0; kwI < 8; ++kwI) {   // 32 k per iter
    s16x8 ah[2], al[2], bhf[4], blf[4];
    #pragma unroll
    for (int f = 0; f < 2; ++f) {
      ah[f] = *(const s16x8*)(A0 + (size_t)(f * 8 + kwI) * 64);
      al[f] = *(const s16x8*)(A1 + (size_t)(f * 8 + kwI) * 64);
    }
    #pragma unroll
    for (int g = 0; g < 4; ++g) {
      bhf[g] = *(const s16x8*)(B0 + (size_t)(g * 8 + kwI) * 64);
      blf[g] = *(const s16x8*)(B1 + (size_t)(g * 8 + kwI) * 64);
    }
    #pragma unroll
    for (int f = 0; f < 2; ++f)
      #pragma unroll
      for (int g = 0; g < 4; ++g) {
        acc[f][g] = __builtin_amdgcn_mfma_f32_16x16x32_bf16(ah[f], bhf[g], acc[f][g], 0, 0, 0);
        acc[f][g] = __builtin_amdgcn_mfma_f32_16x16x32_bf16(ah[f], blf[g], acc[f][g], 0, 0, 0);
        acc[f][g] = __builtin_amdgcn_mfma_f32_16x16x32_bf16(al[f], bhf[g], acc[f][g], 0, 0, 0);
      }
  }

  // --- vsrc/vdst from acc [verified], prescaled by log2(e) ---
  {
    float as4[4], ad4[4];
    #pragma unroll
    for (int g = 0; g < 4; ++g) {
      as4[g] = a_src[head * CFOUT + g * 16 + l15];
      ad4[g] = a_dst[head * CFOUT + g * 16 + l15];
    }
    #pragma unroll
    for (int f = 0; f < 2; ++f) {
      float ps[4] = {0.f, 0.f, 0.f, 0.f}, pd[4] = {0.f, 0.f, 0.f, 0.f};
      #pragma unroll
      for (int g = 0; g < 4; ++g)
        #pragma unroll
        for (int q = 0; q < 4; ++q) {
          float tv = tanhf(acc[f][g][q]);
          ps[q] += tv * as4[g];
          pd[q] += tv * ad4[g];
        }
      #pragma unroll
      for (int q = 0; q < 4; ++q) {
        #pragma unroll
        for (int mm = 1; mm < 16; mm <<= 1) {
          ps[q] += __shfl_xor(ps[q], mm, 64);
          pd[q] += __shfl_xor(pd[q], mm, 64);
        }
      }
      if (l15 == 0) {
        #pragma unroll
        for (int q = 0; q < 4; ++q) {
          int row = row0 + f * 16 + g4 * 4 + q;
          vsrc[(size_t)bh * CN + row] = ps[q] * LOG2E;
          vdst[(size_t)bh * CN + row] = pd[q] * LOG2E;
        }
      }
    }
  }

  // --- fragment-native fB split via per-wave LDS tile [verified] ---
  {
    float* tw = tileT[wid];
    #pragma unroll
    for (int f = 0; f < 2; ++f)
      #pragma unroll
      for (int g = 0; g < 4; ++g)
        #pragma unroll
        for (int q = 0; q < 4; ++q)
          tw[(g * 16 + l15) * 33 + f * 16 + g4 * 4 + q] = acc[f][g][q];
    const int JT = (blk & 7) * 4 + wid;    // global j-tile = row0/32
    #pragma unroll
    for (int g = 0; g < 4; ++g) {
      float v[8];
      #pragma unroll
      for (int r = 0; r < 8; ++r)
        v[r] = tw[(g * 16 + l15) * 33 + g4 * 8 + r];
      unsigned int hw[4], lw[4];
      #pragma unroll
      for (int p = 0; p < 4; ++p) {
        float x0 = v[2 * p], x1 = v[2 * p + 1];
        short h0 = f2bf(x0), h1 = f2bf(x1);
        hw[p] = (unsigned int)(unsigned short)h0 | ((unsigned int)(unsigned short)h1 << 16);
        lw[p] = pkhi(x0 - bf2f(h0), x1 - bf2f(h1));
      }
      size_t base = (((size_t)bh * 32 + JT) * 4 + g) * 256 + (size_t)lane * 4;
      *(uint4*)(fBh + base) = make_uint4(hw[0], hw[1], hw[2], hw[3]);
      *(uint4*)(fBl + base) = make_uint4(lw[0], lw[1], lw[2], lw[3]);
    }
  }
}

// ---------------------------------------------------------------------------
// attn [round-16 verified per-step code, f extended 2->4; 64 i-rows/block]:
// 1024 blocks x 256 thr (4 waves); wave = j-quarter of one 64-row i-tile.
// Amortizes B-fragment loads / dK prep / loop overhead over 2x scores and
// forces the compiler off the 64-VGPR straitjacket (40KB LDS -> 4 blocks/CU).
// ---------------------------------------------------------------------------
__global__ __launch_bounds__(256) void gat_attn_mfma(
    const unsigned int* __restrict__ maskT,
    const unsigned int* __restrict__ fBh, const unsigned int* __restrict__ fBl,
    const float* __restrict__ vsrc, const float* __restrict__ vdst,
    float* __restrict__ out) {
  __shared__ float ldsm[2 * 80 * 64];   // [slot][comp 0..79][lane], 40KB
  const int t = threadIdx.x, lane = t & 63, wid = t >> 6;
  const int bid = blockIdx.x;
  const int blk = (bid & 7) * 128 + (bid >> 3);  // XCD swizzle: 8 bh per XCD
  const int bh = blk >> 4, b = bh >> 3;
  const int i0 = (blk & 15) * 64;
  const int l15 = lane & 15, g4 = lane >> 4;

  const float* dstp = vdst + (size_t)bh * CN;    // already ×log2e

  float M = -INFINITY;
  #pragma unroll
  for (int s_ = 0; s_ < 16; ++s_) M = fmaxf(M, dstp[s_ * 64 + lane]);
  #pragma unroll
  for (int mm = 32; mm; mm >>= 1) M = fmaxf(M, __shfl_xor(M, mm, 64));

  float sA[4], sB[4];
  #pragma unroll
  for (int f = 0; f < 4; ++f) {
    float sv = vsrc[(size_t)bh * CN + i0 + f * 16 + l15];  // ×log2e
    float c = sv + M;
    c = fmaxf(c, 0.2f * c);            // cK = LR(svK + MK) >= row max (K>0)
    sA[f] = sv - c;
    sB[f] = 0.2f * sv - c;
  }

  f32x4 acc[4][4], accL[4];
  #pragma unroll
  for (int f = 0; f < 4; ++f) {
    accL[f] = (f32x4){0.f, 0.f, 0.f, 0.f};
    #pragma unroll
    for (int g = 0; g < 4; ++g) acc[f][g] = (f32x4){0.f, 0.f, 0.f, 0.f};
  }

  s16x8 ones;
  {
    union { s16x8 v; unsigned int u[4]; } uo;
    unsigned int ow = (l15 == 0) ? 0x3F803F80u : 0u;
    uo.u[0] = uo.u[1] = uo.u[2] = uo.u[3] = ow;
    ones = uo.v;
  }

  const s16x8* FH = (const s16x8*)fBh + (size_t)bh * 128 * 64;
  const s16x8* FL = (const s16x8*)fBl + (size_t)bh * 128 * 64;
  const unsigned int* mT = maskT + (size_t)b * 32 * 1024;
  const int jbase = wid * 256;

  for (int j0 = jbase; j0 < jbase + 256; j0 += 32) {
    const float* dj = dstp + j0 + g4 * 8;
    float4 d0 = *(const float4*)&dj[0];
    float4 d1 = *(const float4*)&dj[4];
    float dK[8];
    dK[0] = d0.x; dK[1] = d0.y; dK[2] = d0.z; dK[3] = d0.w;
    dK[4] = d1.x; dK[5] = d1.y; dK[6] = d1.z; dK[7] = d1.w;

    const int fb0 = (j0 >> 5) * 4;
    s16x8 bhf[4], blf[4];
    #pragma unroll
    for (int g = 0; g < 4; ++g) {
      bhf[g] = FH[(size_t)(fb0 + g) * 64 + lane];
      blf[g] = FL[(size_t)(fb0 + g) * 64 + lane];
    }

    #pragma unroll
    for (int f = 0; f < 4; ++f) {
      unsigned int word = mT[(size_t)(j0 >> 5) * 1024 + i0 + f * 16 + l15];
      unsigned int byte = (word >> (g4 * 8)) & 0xFFu;
      float e[8];
      #pragma unroll
      for (int r = 0; r < 8; ++r) {
        float lr = fmaxf(sA[f] + dK[r], fmaf(0.2f, dK[r], sB[f]));
        lr = (byte & (1u << r)) ? lr : -500.f;
        e[r] = __builtin_amdgcn_exp2f(lr);
      }
      unsigned int w0, w1, w2, w3;
      asm("v_cvt_pk_bf16_f32 %0, %1, %2" : "=v"(w0) : "v"(e[0]), "v"(e[1]));
      asm("v_cvt_pk_bf16_f32 %0, %1, %2" : "=v"(w1) : "v"(e[2]), "v"(e[3]));
      asm("v_cvt_pk_bf16_f32 %0, %1, %2" : "=v"(w2) : "v"(e[4]), "v"(e[5]));
      asm("v_cvt_pk_bf16_f32 %0, %1, %2" : "=v"(w3) : "v"(e[6]), "v"(e[7]));
      s16x8 ph;
      {
        union { s16x8 v; unsigned int u[4]; } up;
        up.u[0] = w0; up.u[1] = w1; up.u[2] = w2; up.u[3] = w3;
        ph = up.v;
      }
      accL[f] = __builtin_amdgcn_mfma_f32_16x16x32_bf16(ph, ones, accL[f], 0, 0, 0);
      #pragma unroll
      for (int g = 0; g < 4; ++g) {
        acc[f][g] = __builtin_amdgcn_mfma_f32_16x16x32_bf16(ph, bhf[g], acc[f][g], 0, 0, 0);
        acc[f][g] = __builtin_amdgcn_mfma_f32_16x16x32_bf16(ph, blf[g], acc[f][g], 0, 0, 0);
      }
    }
  }

  // ---- 2-phase 4-way merge [verified structure; comps 0..79] ----
  if (wid >= 2) {
    float* s = ldsm + (size_t)(wid - 2) * 80 * 64 + lane;
    #pragma unroll
    for (int f = 0; f < 4; ++f) {
      #pragma unroll
      for (int g = 0; g < 4; ++g)
        #pragma unroll
        for (int q = 0; q < 4; ++q)
          s[((f * 4 + g) * 4 + q) * 64] = acc[f][g][q];
      #pragma unroll
      for (int q = 0; q < 4; ++q)
        s[(64 + f * 4 + q) * 64] = accL[f][q];
    }
  }
  __syncthreads();
  if (wid < 2) {
    const float* s = ldsm + (size_t)wid * 80 * 64 + lane;
    #pragma unroll
    for (int f = 0; f < 4; ++f) {
      #pragma unroll
      for (int g = 0; g < 4; ++g)
        #pragma unroll
        for (int q = 0; q < 4; ++q)
          acc[f][g][q] += s[((f * 4 + g) * 4 + q) * 64];
      #pragma unroll
      for (int q = 0; q < 4; ++q)
        accL[f][q] += s[(64 + f * 4 + q) * 64];
    }
  }
  if (wid == 1) {
    float* s = ldsm + (size_t)80 * 64 + lane;
    #pragma unroll
    for (int f = 0; f < 4; ++f) {
      #pragma unroll
      for (int g = 0; g < 4; ++g)
        #pragma unroll
        for (int q = 0; q < 4; ++q)
          s[((f * 4 + g) * 4 + q) * 64] = acc[f][g][q];
      #pragma unroll
      for (int q = 0; q < 4; ++q)
        s[(64 + f * 4 + q) * 64] = accL[f][q];
    }
  }
  __syncthreads();
  if (wid == 0) {
    const float* s = ldsm + (size_t)80 * 64 + lane;
    #pragma unroll
    for (int f = 0; f < 4; ++f) {
      #pragma unroll
      for (int g = 0; g < 4; ++g)
        #pragma unroll
        for (int q = 0; q < 4; ++q)
          acc[f][g][q] += s[((f * 4 + g) * 4 + q) * 64];
      #pragma unroll
      for (int q = 0; q < 4; ++q)
        accL[f][q] += s[(64 + f * 4 + q) * 64];
    }

    #pragma unroll
    for (int f = 0; f < 4; ++f) {
      float linv[4];
      #pragma unroll
      for (int q = 0; q < 4; ++q)
        linv[q] = 1.0f / __shfl(accL[f][q], g4 << 4, 64);
      #pragma unroll
      for (int g = 0; g < 4; ++g)
        #pragma unroll
        for (int q = 0; q < 4; ++q) {
          int row = i0 + f * 16 + g4 * 4 + q;
          int col = g * 16 + l15;
          out[((size_t)bh * CN + row) * CFOUT + col] = acc[f][g][q] * linv[q];
        }
    }
  }
}

extern "C" void kernel_launch(void* const* d_in, const int* in_sizes, int n_in,
                              void* d_out, int out_size, void* d_ws, size_t ws_size,
                              hipStream_t stream) {
  const float* h     = (const float*)d_in[0];
  const int*   adj   = (const int*)d_in[1];
  const float* w     = (const float*)d_in[2];
  const float* a_src = (const float*)d_in[3];
  const float* a_dst = (const float*)d_in[4];
  float* out = (float*)d_out;

  // ws layout (26MB, round-14/16-proven):
  //   [ 0M.. 4M) hh   [ 4M.. 8M) hl
  //   [ 8M..16M) fBh  [16M..24M) fBl
  //   [24M..24.5M) wh|wl  [24.5M..25M) vsrc|vdst  [25M..26M) maskT
  char* p = (char*)d_ws;
  unsigned int* hh  = (unsigned int*)p;
  unsigned int* hl  = (unsigned int*)(p + (size_t)(4u << 20));
  unsigned int* fBh = (unsigned int*)(p + (size_t)(8u << 20));
  unsigned int* fBl = (unsigned int*)(p + (size_t)(16u << 20));
  unsigned int* wh  = (unsigned int*)(p + (size_t)(24u << 20));
  unsigned int* wl  = (unsigned int*)(p + (size_t)(24u << 20) + (256u << 10));
  float* vs  = (float*)(p + (size_t)(24u << 20) + (512u << 10));
  float* vd  = (float*)(p + (size_t)(24u << 20) + (768u << 10));
  unsigned int* maskT = (unsigned int*)(p + (size_t)(25u << 20));

  hipLaunchKernelGGL(prep, dim3(1032 + 2048), dim3(256), 0, stream,
                     h, w, adj, hh, hl, wh, wl, maskT);
  hipLaunchKernelGGL(liteF, dim3(512), dim3(256), 0, stream,
                     hh, hl, wh, wl, a_src, a_dst, fBh, fBl, vs, vd);
  hipLaunchKernelGGL(gat_attn_mfma, dim3(1024), dim3(256), 0, stream,
                     maskT, fBh, fBl, vs, vd, out);
}

// Round 18
// 62.268 us; speedup vs baseline: 1.1817x; 1.1817x over previous
//
#include <hip/hip_runtime.h>
#include <math.h>

constexpr int CBS   = 8;
constexpr int CN    = 1024;
constexpr int CFIN  = 256;
constexpr int CNH   = 8;
constexpr int CFOUT = 64;

using f32x4 = __attribute__((ext_vector_type(4))) float;
using s16x8 = __attribute__((ext_vector_type(8))) short;

__device__ __forceinline__ short f2bf(float x) {
  __bf16 b = (__bf16)x;
  return __builtin_bit_cast(short, b);
}
__device__ __forceinline__ float bf2f(short s) {
  __bf16 b = __builtin_bit_cast(__bf16, s);
  return (float)b;
}
__device__ __forceinline__ unsigned int pkhi(float a, float b) {
  return (unsigned int)(unsigned short)f2bf(a) |
         ((unsigned int)(unsigned short)f2bf(b) << 16);
}

// ---------------------------------------------------------------------------
// prep [VERIFIED r14/r16 verbatim]: conv_h -> A-fragment-native hh/hl
// (0..1023), conv_w -> B-fragment-native wh/wl (1024..1031), packT fat-wave
// -> maskT[b][jw32][i] (1032..3079).
// ---------------------------------------------------------------------------
__global__ __launch_bounds__(256) void prep(
    const float* __restrict__ h, const float* __restrict__ w,
    const int* __restrict__ adj,
    unsigned int* __restrict__ hh, unsigned int* __restrict__ hl,
    unsigned int* __restrict__ wh, unsigned int* __restrict__ wl,
    unsigned int* __restrict__ maskT) {
  const int blk = blockIdx.x, t = threadIdx.x;
  if (blk < 1024) {
    size_t i = (size_t)blk * 256 + t;          // uint4 index in [0, 262144)
    const int gi = (int)(i & 31);
    const int n  = (int)((i >> 5) & 1023);
    const int b  = (int)(i >> 15);
    const float4* src = (const float4*)(h + i * 8);
    float4 a = src[0], bb = src[1];
    float v[8] = {a.x, a.y, a.z, a.w, bb.x, bb.y, bb.z, bb.w};
    unsigned int hw[4], lw[4];
    #pragma unroll
    for (int p = 0; p < 4; ++p) {
      float x0 = v[2 * p], x1 = v[2 * p + 1];
      short h0 = f2bf(x0), h1 = f2bf(x1);
      hw[p] = (unsigned int)(unsigned short)h0 | ((unsigned int)(unsigned short)h1 << 16);
      lw[p] = pkhi(x0 - bf2f(h0), x1 - bf2f(h1));
    }
    const int RT = n >> 4, l15v = n & 15, kwI = gi >> 2, g4v = gi & 3;
    size_t dst = (((size_t)b * 64 + RT) * 8 + kwI) * 64 + (g4v * 16 + l15v);
    ((uint4*)hh)[dst] = make_uint4(hw[0], hw[1], hw[2], hw[3]);
    ((uint4*)hl)[dst] = make_uint4(lw[0], lw[1], lw[2], lw[3]);
  } else if (blk < 1032) {
    const int head = blk - 1024;
    const int o = t & 63, kc = (t >> 6) * 64;
    const int g = o >> 4, l15v = o & 15;
    const float* wg = w + (size_t)head * CFIN * CFOUT;
    #pragma unroll
    for (int j = 0; j < 8; ++j) {
      const int gi = (kc >> 3) + j;            // 0..31
      const int kwI = gi >> 2, g4v = gi & 3;
      unsigned int hw[4], lw[4];
      #pragma unroll
      for (int p = 0; p < 4; ++p) {
        int k = gi * 8 + 2 * p;
        float x0 = wg[(size_t)k * 64 + o], x1 = wg[(size_t)(k + 1) * 64 + o];
        short h0 = f2bf(x0), h1 = f2bf(x1);
        hw[p] = (unsigned int)(unsigned short)h0 | ((unsigned int)(unsigned short)h1 << 16);
        lw[p] = pkhi(x0 - bf2f(h0), x1 - bf2f(h1));
      }
      size_t dst = (((size_t)head * 4 + g) * 8 + kwI) * 64 + (g4v * 16 + l15v);
      ((uint4*)wh)[dst] = make_uint4(hw[0], hw[1], hw[2], hw[3]);
      ((uint4*)wl)[dst] = make_uint4(lw[0], lw[1], lw[2], lw[3]);
    }
  } else {
    const int lane = t & 63, wv = t >> 6;
    const long long bi = (long long)(blk - 1032) * 4 + wv;   // b*1024 + i
    const int b = (int)(bi >> 10), i = (int)(bi & 1023);
    const int* ap = adj + bi * 1024 + lane;
    int a[16];
    #pragma unroll
    for (int jw = 0; jw < 16; ++jw) a[jw] = ap[jw * 64];     // 16 loads in flight
    #pragma unroll
    for (int jw = 0; jw < 16; ++jw) {
      unsigned long long m = __ballot(a[jw] > 0);
      if (lane == 0) {
        maskT[((size_t)b * 32 + jw * 2 + 0) * 1024 + i] = (unsigned int)m;
        maskT[((size_t)b * 32 + jw * 2 + 1) * 1024 + i] = (unsigned int)(m >> 32);
      }
    }
  }
}

// ---------------------------------------------------------------------------
// liteF [VERIFIED r14/r16 verbatim]: 512 blocks. hp = h@w via hi/lo 3-MFMA
// split (fragment-native A/B loads); epilogue writes vsrc/vdst (×log2e) and
// fragment-native fB hi/lo.
// ---------------------------------------------------------------------------
__global__ __launch_bounds__(256) void liteF(
    const unsigned int* __restrict__ hh, const unsigned int* __restrict__ hl,
    const unsigned int* __restrict__ wh, const unsigned int* __restrict__ wl,
    const float* __restrict__ a_src, const float* __restrict__ a_dst,
    unsigned int* __restrict__ fBh, unsigned int* __restrict__ fBl,
    float* __restrict__ vsrc, float* __restrict__ vdst) {
  __shared__ float tileT[4][64 * 33];   // per-wave [o][n_local], pad 33
  const int bid = blockIdx.x, t = threadIdx.x;
  const int lane = t & 63, wid = t >> 6;
  const int blk = (bid & 7) * 64 + (bid >> 3);   // XCD swizzle: one b per XCD
  const int bh = blk >> 3, head = bh & 7, b = bh >> 3;
  const int row0 = (blk & 7) * 128 + wid * 32;
  const int l15 = lane & 15, g4 = lane >> 4;
  const float LOG2E = 1.44269504088896340736f;

  const uint4* A0 = (const uint4*)hh + (((size_t)b * 64 + (row0 >> 4)) * 8) * 64 + lane;
  const uint4* A1 = (const uint4*)hl + (((size_t)b * 64 + (row0 >> 4)) * 8) * 64 + lane;
  const uint4* B0 = (const uint4*)wh + ((size_t)head * 4 * 8) * 64 + lane;
  const uint4* B1 = (const uint4*)wl + ((size_t)head * 4 * 8) * 64 + lane;

  f32x4 acc[2][4];
  #pragma unroll
  for (int f = 0; f < 2; ++f)
    #pragma unroll
    for (int g = 0; g < 4; ++g) acc[f][g] = (f32x4){0.f, 0.f, 0.f, 0.f};

  for (int kwI = 0; kwI < 8; ++kwI) {   // 32 k per iter
    s16x8 ah[2], al[2], bhf[4], blf[4];
    #pragma unroll
    for (int f = 0; f < 2; ++f) {
      ah[f] = *(const s16x8*)(A0 + (size_t)(f * 8 + kwI) * 64);
      al[f] = *(const s16x8*)(A1 + (size_t)(f * 8 + kwI) * 64);
    }
    #pragma unroll
    for (int g = 0; g < 4; ++g) {
      bhf[g] = *(const s16x8*)(B0 + (size_t)(g * 8 + kwI) * 64);
      blf[g] = *(const s16x8*)(B1 + (size_t)(g * 8 + kwI) * 64);
    }
    #pragma unroll
    for (int f = 0; f < 2; ++f)
      #pragma unroll
      for (int g = 0; g < 4; ++g) {
        acc[f][g] = __builtin_amdgcn_mfma_f32_16x16x32_bf16(ah[f], bhf[g], acc[f][g], 0, 0, 0);
        acc[f][g] = __builtin_amdgcn_mfma_f32_16x16x32_bf16(ah[f], blf[g], acc[f][g], 0, 0, 0);
        acc[f][g] = __builtin_amdgcn_mfma_f32_16x16x32_bf16(al[f], bhf[g], acc[f][g], 0, 0, 0);
      }
  }

  // --- vsrc/vdst from acc [verified], prescaled by log2(e) ---
  {
    float as4[4], ad4[4];
    #pragma unroll
    for (int g = 0; g < 4; ++g) {
      as4[g] = a_src[head * CFOUT + g * 16 + l15];
      ad4[g] = a_dst[head * CFOUT + g * 16 + l15];
    }
    #pragma unroll
    for (int f = 0; f < 2; ++f) {
      float ps[4] = {0.f, 0.f, 0.f, 0.f}, pd[4] = {0.f, 0.f, 0.f, 0.f};
      #pragma unroll
      for (int g = 0; g < 4; ++g)
        #pragma unroll
        for (int q = 0; q < 4; ++q) {
          float tv = tanhf(acc[f][g][q]);
          ps[q] += tv * as4[g];
          pd[q] += tv * ad4[g];
        }
      #pragma unroll
      for (int q = 0; q < 4; ++q) {
        #pragma unroll
        for (int mm = 1; mm < 16; mm <<= 1) {
          ps[q] += __shfl_xor(ps[q], mm, 64);
          pd[q] += __shfl_xor(pd[q], mm, 64);
        }
      }
      if (l15 == 0) {
        #pragma unroll
        for (int q = 0; q < 4; ++q) {
          int row = row0 + f * 16 + g4 * 4 + q;
          vsrc[(size_t)bh * CN + row] = ps[q] * LOG2E;
          vdst[(size_t)bh * CN + row] = pd[q] * LOG2E;
        }
      }
    }
  }

  // --- fragment-native fB split via per-wave LDS tile [verified] ---
  {
    float* tw = tileT[wid];
    #pragma unroll
    for (int f = 0; f < 2; ++f)
      #pragma unroll
      for (int g = 0; g < 4; ++g)
        #pragma unroll
        for (int q = 0; q < 4; ++q)
          tw[(g * 16 + l15) * 33 + f * 16 + g4 * 4 + q] = acc[f][g][q];
    const int JT = (blk & 7) * 4 + wid;    // global j-tile = row0/32
    #pragma unroll
    for (int g = 0; g < 4; ++g) {
      float v[8];
      #pragma unroll
      for (int r = 0; r < 8; ++r)
        v[r] = tw[(g * 16 + l15) * 33 + g4 * 8 + r];
      unsigned int hw[4], lw[4];
      #pragma unroll
      for (int p = 0; p < 4; ++p) {
        float x0 = v[2 * p], x1 = v[2 * p + 1];
        short h0 = f2bf(x0), h1 = f2bf(x1);
        hw[p] = (unsigned int)(unsigned short)h0 | ((unsigned int)(unsigned short)h1 << 16);
        lw[p] = pkhi(x0 - bf2f(h0), x1 - bf2f(h1));
      }
      size_t base = (((size_t)bh * 32 + JT) * 4 + g) * 256 + (size_t)lane * 4;
      *(uint4*)(fBh + base) = make_uint4(hw[0], hw[1], hw[2], hw[3]);
      *(uint4*)(fBl + base) = make_uint4(lw[0], lw[1], lw[2], lw[3]);
    }
  }
}

// ---------------------------------------------------------------------------
// attn [CONSOLIDATION: r12's best-measured geometry (512 blocks x 512 thr,
// 8 waves, grp j-split, 2-group LDS merge) + r13's prescaled inputs (no
// LOG2E muls) + r16's verified v_cvt_pk_bf16_f32 packing. No unroll pragma,
// no min-waves hint (r13's regressors).]
// ---------------------------------------------------------------------------
__global__ __launch_bounds__(512) void gat_attn_mfma(
    const unsigned int* __restrict__ maskT,
    const unsigned int* __restrict__ fBh, const unsigned int* __restrict__ fBl,
    const float* __restrict__ vsrc, const float* __restrict__ vdst,
    float* __restrict__ out) {
  __shared__ float ldsm[32 * 256 + 8 * 256];   // 40KB partial merge
  const int t = threadIdx.x, lane = t & 63, wid = t >> 6;
  const int w4 = wid & 3, grp = wid >> 2;
  const int bid = blockIdx.x;
  const int blk = (bid & 7) * 64 + (bid >> 3);   // XCD swizzle: 8 bh per XCD
  const int bh = blk >> 3, b = bh >> 3;
  const int i0 = (blk & 7) * 128 + w4 * 32;
  const int l15 = lane & 15, g4 = lane >> 4;

  const float* dstp = vdst + (size_t)bh * CN;    // already ×log2e

  float M = -INFINITY;
  #pragma unroll
  for (int s_ = 0; s_ < 16; ++s_) M = fmaxf(M, dstp[s_ * 64 + lane]);
  #pragma unroll
  for (int mm = 32; mm; mm >>= 1) M = fmaxf(M, __shfl_xor(M, mm, 64));

  float sA[2], sB[2];
  #pragma unroll
  for (int f = 0; f < 2; ++f) {
    float sv = vsrc[(size_t)bh * CN + i0 + f * 16 + l15];  // ×log2e
    float c = sv + M;
    c = fmaxf(c, 0.2f * c);            // cK = LR(svK + MK) >= row max (K>0)
    sA[f] = sv - c;
    sB[f] = 0.2f * sv - c;
  }

  f32x4 acc[2][4], accL[2];
  #pragma unroll
  for (int f = 0; f < 2; ++f) {
    accL[f] = (f32x4){0.f, 0.f, 0.f, 0.f};
    #pragma unroll
    for (int g = 0; g < 4; ++g) acc[f][g] = (f32x4){0.f, 0.f, 0.f, 0.f};
  }

  s16x8 ones;
  {
    union { s16x8 v; unsigned int u[4]; } uo;
    unsigned int ow = (l15 == 0) ? 0x3F803F80u : 0u;
    uo.u[0] = uo.u[1] = uo.u[2] = uo.u[3] = ow;
    ones = uo.v;
  }

  const s16x8* FH = (const s16x8*)fBh + (size_t)bh * 128 * 64;
  const s16x8* FL = (const s16x8*)fBl + (size_t)bh * 128 * 64;
  const unsigned int* mT = maskT + (size_t)b * 32 * 1024;
  const int jbase = grp * 512;

  for (int j0 = jbase; j0 < jbase + 512; j0 += 32) {
    const float* dj = dstp + j0 + g4 * 8;
    float4 d0 = *(const float4*)&dj[0];
    float4 d1 = *(const float4*)&dj[4];
    float dK[8];
    dK[0] = d0.x; dK[1] = d0.y; dK[2] = d0.z; dK[3] = d0.w;
    dK[4] = d1.x; dK[5] = d1.y; dK[6] = d1.z; dK[7] = d1.w;

    const int fb0 = (j0 >> 5) * 4;
    s16x8 bhf[4], blf[4];
    #pragma unroll
    for (int g = 0; g < 4; ++g) {
      bhf[g] = FH[(size_t)(fb0 + g) * 64 + lane];
      blf[g] = FL[(size_t)(fb0 + g) * 64 + lane];
    }

    #pragma unroll
    for (int f = 0; f < 2; ++f) {
      unsigned int word = mT[(size_t)(j0 >> 5) * 1024 + i0 + f * 16 + l15];
      unsigned int byte = (word >> (g4 * 8)) & 0xFFu;
      float e[8];
      #pragma unroll
      for (int r = 0; r < 8; ++r) {
        float lr = fmaxf(sA[f] + dK[r], fmaf(0.2f, dK[r], sB[f]));
        lr = (byte & (1u << r)) ? lr : -500.f;
        e[r] = __builtin_amdgcn_exp2f(lr);
      }
      unsigned int w0, w1, w2, w3;
      asm("v_cvt_pk_bf16_f32 %0, %1, %2" : "=v"(w0) : "v"(e[0]), "v"(e[1]));
      asm("v_cvt_pk_bf16_f32 %0, %1, %2" : "=v"(w1) : "v"(e[2]), "v"(e[3]));
      asm("v_cvt_pk_bf16_f32 %0, %1, %2" : "=v"(w2) : "v"(e[4]), "v"(e[5]));
      asm("v_cvt_pk_bf16_f32 %0, %1, %2" : "=v"(w3) : "v"(e[6]), "v"(e[7]));
      s16x8 ph;
      {
        union { s16x8 v; unsigned int u[4]; } up;
        up.u[0] = w0; up.u[1] = w1; up.u[2] = w2; up.u[3] = w3;
        ph = up.v;
      }
      accL[f] = __builtin_amdgcn_mfma_f32_16x16x32_bf16(ph, ones, accL[f], 0, 0, 0);
      #pragma unroll
      for (int g = 0; g < 4; ++g) {
        acc[f][g] = __builtin_amdgcn_mfma_f32_16x16x32_bf16(ph, bhf[g], acc[f][g], 0, 0, 0);
        acc[f][g] = __builtin_amdgcn_mfma_f32_16x16x32_bf16(ph, blf[g], acc[f][g], 0, 0, 0);
      }
    }
  }

  // merge group-1 partials into group-0 (lane-major LDS, conflict-free)
  const int tid = t & 255;
  if (grp == 1) {
    #pragma unroll
    for (int f = 0; f < 2; ++f) {
      #pragma unroll
      for (int g = 0; g < 4; ++g)
        #pragma unroll
        for (int q = 0; q < 4; ++q)
          ldsm[((f * 4 + g) * 4 + q) * 256 + tid] = acc[f][g][q];
      #pragma unroll
      for (int q = 0; q < 4; ++q)
        ldsm[8192 + (f * 4 + q) * 256 + tid] = accL[f][q];
    }
  }
  __syncthreads();
  if (grp == 0) {
    #pragma unroll
    for (int f = 0; f < 2; ++f) {
      #pragma unroll
      for (int g = 0; g < 4; ++g)
        #pragma unroll
        for (int q = 0; q < 4; ++q)
          acc[f][g][q] += ldsm[((f * 4 + g) * 4 + q) * 256 + tid];
      #pragma unroll
      for (int q = 0; q < 4; ++q)
        accL[f][q] += ldsm[8192 + (f * 4 + q) * 256 + tid];
    }

    #pragma unroll
    for (int f = 0; f < 2; ++f) {
      float linv[4];
      #pragma unroll
      for (int q = 0; q < 4; ++q)
        linv[q] = 1.0f / __shfl(accL[f][q], g4 << 4, 64);
      #pragma unroll
      for (int g = 0; g < 4; ++g)
        #pragma unroll
        for (int q = 0; q < 4; ++q) {
          int row = i0 + f * 16 + g4 * 4 + q;
          int col = g * 16 + l15;
          out[((size_t)bh * CN + row) * CFOUT + col] = acc[f][g][q] * linv[q];
        }
    }
  }
}

extern "C" void kernel_launch(void* const* d_in, const int* in_sizes, int n_in,
                              void* d_out, int out_size, void* d_ws, size_t ws_size,
                              hipStream_t stream) {
  const float* h     = (const float*)d_in[0];
  const int*   adj   = (const int*)d_in[1];
  const float* w     = (const float*)d_in[2];
  const float* a_src = (const float*)d_in[3];
  const float* a_dst = (const float*)d_in[4];
  float* out = (float*)d_out;

  // ws layout (26MB, proven):
  //   [ 0M.. 4M) hh   [ 4M.. 8M) hl
  //   [ 8M..16M) fBh  [16M..24M) fBl
  //   [24M..24.5M) wh|wl  [24.5M..25M) vsrc|vdst  [25M..26M) maskT
  char* p = (char*)d_ws;
  unsigned int* hh  = (unsigned int*)p;
  unsigned int* hl  = (unsigned int*)(p + (size_t)(4u << 20));
  unsigned int* fBh = (unsigned int*)(p + (size_t)(8u << 20));
  unsigned int* fBl = (unsigned int*)(p + (size_t)(16u << 20));
  unsigned int* wh  = (unsigned int*)(p + (size_t)(24u << 20));
  unsigned int* wl  = (unsigned int*)(p + (size_t)(24u << 20) + (256u << 10));
  float* vs  = (float*)(p + (size_t)(24u << 20) + (512u << 10));
  float* vd  = (float*)(p + (size_t)(24u << 20) + (768u << 10));
  unsigned int* maskT = (unsigned int*)(p + (size_t)(25u << 20));

  hipLaunchKernelGGL(prep, dim3(1032 + 2048), dim3(256), 0, stream,
                     h, w, adj, hh, hl, wh, wl, maskT);
  hipLaunchKernelGGL(liteF, dim3(512), dim3(256), 0, stream,
                     hh, hl, wh, wl, a_src, a_dst, fBh, fBl, vs, vd);
  hipLaunchKernelGGL(gat_attn_mfma, dim3(512), dim3(512), 0, stream,
                     maskT, fBh, fBl, vs, vd, out);
}